// Round 1
// baseline (200.282 us; speedup 1.0000x reference)
//
#include <hip/hip_runtime.h>

typedef unsigned short u16;
typedef __bf16 bf16x8 __attribute__((ext_vector_type(8)));
typedef float f32x4 __attribute__((ext_vector_type(4)));
typedef unsigned short u16x8 __attribute__((ext_vector_type(8)));

#define NB 4
#define NS 2048
#define ND 192
#define NH 8
#define HD 24
#define HDP 32
#define NM (NB*NS)          // 8192 rows
#define N3 (3*ND)           // 576

#define LOG2E 1.4426950408889634f
// 1/sqrt(24) * log2(e): fold softmax scale and exp->exp2 conversion into Q
#define QSCALE (0.20412414523193152f * 1.4426950408889634f)

__device__ __forceinline__ u16 f2bf(float f){
  union { float f; unsigned u; } a; a.f = f;
  unsigned r = a.u + 0x7fffu + ((a.u >> 16) & 1u);   // round-to-nearest-even
  return (u16)(r >> 16);
}

// ---------------------------------------------------------------- prep ----
// x (fp32) -> bf16 ; w_attn [192][576] -> wta [576][192] bf16 (n-major);
// w_proj [192][192] -> wtp [192][192] bf16 (n-major)
__global__ __launch_bounds__(256) void prep_kernel(
    const float* __restrict__ x, const float* __restrict__ w_attn,
    const float* __restrict__ w_proj,
    u16* __restrict__ xb, u16* __restrict__ wta, u16* __restrict__ wtp)
{
  const int NXQ = NM*ND/4;                 // 393216 float4 quads
  int i = blockIdx.x*256 + threadIdx.x;
  if (i < NXQ) {
    float4 v = reinterpret_cast<const float4*>(x)[i];
    u16 o[4] = { f2bf(v.x), f2bf(v.y), f2bf(v.z), f2bf(v.w) };
    *reinterpret_cast<uint2*>(xb + i*4) = *reinterpret_cast<uint2*>(o);
  } else if (i < NXQ + N3*ND) {
    int j = i - NXQ; int n = j / ND; int k = j % ND;
    wta[n*ND + k] = f2bf(w_attn[k*N3 + n]);
  } else if (i < NXQ + N3*ND + ND*ND) {
    int j = i - NXQ - N3*ND; int n = j / ND; int k = j % ND;
    wtp[n*ND + k] = f2bf(w_proj[k*ND + n]);
  }
}

// ----------------------------------------------------------------- qkv ----
// [8192,192] @ [192,576] + b -> scatter to qp/kp/vp [B][H][S][32] bf16
__global__ __launch_bounds__(256) void qkv_kernel(
    const u16* __restrict__ xb, const u16* __restrict__ wta,
    const float* __restrict__ b_attn,
    u16* __restrict__ qp, u16* __restrict__ kp, u16* __restrict__ vp)
{
  const int m0 = blockIdx.x*64, n0 = blockIdx.y*64;
  const int tid = threadIdx.x;
  const int w = tid >> 6, lane = tid & 63, c = lane & 15, g = lane >> 4;
  f32x4 acc[4] = {{0,0,0,0},{0,0,0,0},{0,0,0,0},{0,0,0,0}};
  const int ar = m0 + w*16 + c;
  #pragma unroll
  for (int ks = 0; ks < 6; ++ks) {
    bf16x8 af = *(const bf16x8*)(xb + ar*ND + ks*32 + g*8);
    #pragma unroll
    for (int t = 0; t < 4; ++t) {
      bf16x8 bfr = *(const bf16x8*)(wta + (n0 + t*16 + c)*ND + ks*32 + g*8);
      acc[t] = __builtin_amdgcn_mfma_f32_16x16x32_bf16(af, bfr, acc[t], 0, 0, 0);
    }
  }
  #pragma unroll
  for (int t = 0; t < 4; ++t) {
    int n  = n0 + t*16 + c;
    int tn = n / ND;            // 0=Q 1=K 2=V
    int id = n % ND;
    int h  = id / HD, d = id % HD;
    u16* dst = (tn == 0) ? qp : ((tn == 1) ? kp : vp);
    float bias = b_attn[n];
    float scl  = (tn == 0) ? QSCALE : 1.0f;
    #pragma unroll
    for (int r = 0; r < 4; ++r) {
      int m = m0 + w*16 + g*4 + r;
      int b = m >> 11, s = m & (NS-1);
      float val = (acc[t][r] + bias) * scl;
      dst[((((size_t)b*NH + h)*NS + s) << 5) + d] = f2bf(val);
    }
  }
}

// ---------------------------------------------------------------- attn ----
// flash attention, causal; one block = 64 q-rows of one (b,h); 4 waves
__global__ __launch_bounds__(256) void attn_kernel(
    const u16* __restrict__ qp, const u16* __restrict__ kp,
    const u16* __restrict__ vp, const float* __restrict__ mask0,
    u16* __restrict__ ao)
{
  __shared__ u16 vt[32][72];     // V^T tile, padded (+8) against bank conflicts
  __shared__ u16 plds[64][72];   // P re-fragment buffer, per-wave 16-row slices
  const int qt = (int)gridDim.x - 1 - (int)blockIdx.x;   // heavy tiles first
  const int bh = blockIdx.y;
  const int b = bh >> 3, h = bh & 7;
  const int tid = threadIdx.x;
  const int w = tid >> 6, lane = tid & 63, c = lane & 15, g = lane >> 4;
  const int q0 = qt * 64;
  const size_t hb = (size_t)bh * NS * HDP;
  const u16* qb = qp + hb;
  const u16* kb = kp + hb;
  const u16* vb = vp + hb;
  const float* mrow = mask0 + b*NS;

  bf16x8 qf = *(const bf16x8*)(qb + (q0 + w*16 + c)*HDP + g*8);

  f32x4 o0 = {0,0,0,0}, o1 = {0,0,0,0};
  float m_r[4] = {-1e30f,-1e30f,-1e30f,-1e30f};
  float l_r[4] = {0.f,0.f,0.f,0.f};

  const int kk = tid & 63, dg = tid >> 6;

  for (int jt = 0; jt <= qt; ++jt) {
    const int k0 = jt * 64;
    // ---- stage V^T (rows 24..31 zeroed: pads) ----
    if (dg < 3) {
      u16x8 vr = *(const u16x8*)(vb + (k0 + kk)*HDP + dg*8);
      #pragma unroll
      for (int j = 0; j < 8; ++j) vt[dg*8 + j][kk] = vr[j];
    } else {
      #pragma unroll
      for (int j = 0; j < 8; ++j) vt[24 + j][kk] = 0;
    }
    __syncthreads();

    // ---- QK^T : 4 MFMAs, B-frags straight from global (L1/L2-hot) ----
    f32x4 sacc[4];
    #pragma unroll
    for (int t = 0; t < 4; ++t) {
      bf16x8 kf = *(const bf16x8*)(kb + (k0 + t*16 + c)*HDP + g*8);
      f32x4 z = {0,0,0,0};
      sacc[t] = __builtin_amdgcn_mfma_f32_16x16x32_bf16(qf, kf, z, 0, 0, 0);
    }
    float mk[4];
    #pragma unroll
    for (int t = 0; t < 4; ++t) mk[t] = mrow[k0 + t*16 + c] * LOG2E;

    // ---- mask + online softmax (exp2 domain; scale folded into Q) ----
    const bool diag = (jt == qt);
    float pm[4];
    #pragma unroll
    for (int r = 0; r < 4; ++r) {
      const int q = q0 + w*16 + g*4 + r;
      float sm = -1e30f;
      #pragma unroll
      for (int t = 0; t < 4; ++t) {
        float s = sacc[t][r] + mk[t];
        if (diag && (k0 + t*16 + c) > q) s = -3e38f;
        sacc[t][r] = s;
        sm = fmaxf(sm, s);
      }
      pm[r] = sm;
    }
    #pragma unroll
    for (int off = 1; off < 16; off <<= 1) {
      #pragma unroll
      for (int r = 0; r < 4; ++r) pm[r] = fmaxf(pm[r], __shfl_xor(pm[r], off));
    }
    float al[4], rs[4];
    #pragma unroll
    for (int r = 0; r < 4; ++r) {
      float mnew = fmaxf(m_r[r], pm[r]);
      al[r] = __builtin_amdgcn_exp2f(m_r[r] - mnew);
      m_r[r] = mnew;
      float s0 = 0.f;
      #pragma unroll
      for (int t = 0; t < 4; ++t) {
        float p = __builtin_amdgcn_exp2f(sacc[t][r] - mnew);
        s0 += p;
        plds[w*16 + g*4 + r][t*16 + c] = f2bf(p);
      }
      rs[r] = s0;
    }
    #pragma unroll
    for (int off = 1; off < 16; off <<= 1) {
      #pragma unroll
      for (int r = 0; r < 4; ++r) rs[r] += __shfl_xor(rs[r], off);
    }
    f32x4 alv = {al[0], al[1], al[2], al[3]};
    #pragma unroll
    for (int r = 0; r < 4; ++r) l_r[r] = l_r[r]*al[r] + rs[r];
    o0 *= alv; o1 *= alv;

    // ---- PV : P A-frags via LDS, V^T B-frags ----
    bf16x8 pa0 = *(const bf16x8*)(&plds[w*16 + c][g*8]);
    bf16x8 pa1 = *(const bf16x8*)(&plds[w*16 + c][32 + g*8]);
    bf16x8 v00 = *(const bf16x8*)(&vt[c][g*8]);
    bf16x8 v01 = *(const bf16x8*)(&vt[c][32 + g*8]);
    bf16x8 v10 = *(const bf16x8*)(&vt[16 + c][g*8]);
    bf16x8 v11 = *(const bf16x8*)(&vt[16 + c][32 + g*8]);
    o0 = __builtin_amdgcn_mfma_f32_16x16x32_bf16(pa0, v00, o0, 0, 0, 0);
    o0 = __builtin_amdgcn_mfma_f32_16x16x32_bf16(pa1, v01, o0, 0, 0, 0);
    o1 = __builtin_amdgcn_mfma_f32_16x16x32_bf16(pa0, v10, o1, 0, 0, 0);
    o1 = __builtin_amdgcn_mfma_f32_16x16x32_bf16(pa1, v11, o1, 0, 0, 0);
    __syncthreads();   // protect vt before next stage
  }

  // ---- epilogue: normalize + write [B,S,D] bf16 ----
  #pragma unroll
  for (int r = 0; r < 4; ++r) {
    float inv = 1.0f / l_r[r];
    int q = q0 + w*16 + g*4 + r;
    size_t ro = ((size_t)b*NS + q)*ND + h*HD;
    ao[ro + c] = f2bf(o0[r]*inv);
    if (c < 8) ao[ro + 16 + c] = f2bf(o1[r]*inv);
  }
}

// ---------------------------------------------------------------- proj ----
__global__ __launch_bounds__(256) void proj_kernel(
    const u16* __restrict__ ao, const u16* __restrict__ wtp,
    const float* __restrict__ bp, float* __restrict__ out)
{
  const int m0 = blockIdx.x*64, n0 = blockIdx.y*64;
  const int tid = threadIdx.x;
  const int w = tid >> 6, lane = tid & 63, c = lane & 15, g = lane >> 4;
  f32x4 acc[4] = {{0,0,0,0},{0,0,0,0},{0,0,0,0},{0,0,0,0}};
  const int ar = m0 + w*16 + c;
  #pragma unroll
  for (int ks = 0; ks < 6; ++ks) {
    bf16x8 af = *(const bf16x8*)(ao + ar*ND + ks*32 + g*8);
    #pragma unroll
    for (int t = 0; t < 4; ++t) {
      bf16x8 bfr = *(const bf16x8*)(wtp + (n0 + t*16 + c)*ND + ks*32 + g*8);
      acc[t] = __builtin_amdgcn_mfma_f32_16x16x32_bf16(af, bfr, acc[t], 0, 0, 0);
    }
  }
  #pragma unroll
  for (int t = 0; t < 4; ++t) {
    int n = n0 + t*16 + c;
    float bias = bp[n];
    #pragma unroll
    for (int r = 0; r < 4; ++r) {
      int m = m0 + w*16 + g*4 + r;
      out[(size_t)m*ND + n] = acc[t][r] + bias;
    }
  }
}

// -------------------------------------------------------------- launch ----
extern "C" void kernel_launch(void* const* d_in, const int* in_sizes, int n_in,
                              void* d_out, int out_size, void* d_ws, size_t ws_size,
                              hipStream_t stream)
{
  const float* x      = (const float*)d_in[0];
  const float* mask0  = (const float*)d_in[1];
  const float* w_attn = (const float*)d_in[2];
  const float* b_attn = (const float*)d_in[3];
  const float* w_proj = (const float*)d_in[4];
  const float* b_proj = (const float*)d_in[5];
  float* out = (float*)d_out;

  char* ws = (char*)d_ws;
  u16* qp  = (u16*)(ws);                              // 4 MB  [B][H][S][32]
  u16* kp  = (u16*)(ws + ((size_t)4  << 20));         // 4 MB
  u16* vp  = (u16*)(ws + ((size_t)8  << 20));         // 4 MB
  u16* xb  = (u16*)(ws + ((size_t)12 << 20));         // 3 MB  x bf16
  u16* wta = (u16*)(ws + ((size_t)15 << 20));         // 216 KB
  u16* wtp = (u16*)(ws + ((size_t)15 << 20) + 256*1024);  // 72 KB
  u16* ao  = (u16*)(ws + ((size_t)15 << 20) + 512*1024);  // 3 MB attn out bf16

  // zero Q/K pad lanes (d=24..31) — ws is poisoned before every call
  hipMemsetAsync(ws, 0, (size_t)8 << 20, stream);

  prep_kernel<<<2112, 256, 0, stream>>>(x, w_attn, w_proj, xb, wta, wtp);
  qkv_kernel<<<dim3(NM/64, N3/64), 256, 0, stream>>>(xb, wta, b_attn, qp, kp, vp);
  attn_kernel<<<dim3(NS/64, NB*NH), 256, 0, stream>>>(qp, kp, vp, mask0, ao);
  proj_kernel<<<dim3(NM/64, ND/64), 256, 0, stream>>>(ao, wtp, b_proj, out);
}

// Round 2
// 160.889 us; speedup vs baseline: 1.2449x; 1.2449x over previous
//
#include <hip/hip_runtime.h>

typedef unsigned short u16;
typedef unsigned int u32;
typedef __bf16 bf16x8 __attribute__((ext_vector_type(8)));
typedef float f32x4 __attribute__((ext_vector_type(4)));
typedef float f32x16 __attribute__((ext_vector_type(16)));
typedef u32 u32x2 __attribute__((ext_vector_type(2)));
typedef u32 u32x4 __attribute__((ext_vector_type(4)));

#define NB 4
#define NS 2048
#define ND 192
#define NH 8
#define HD 24
#define NM (NB*NS)          // 8192 rows
#define N3 (3*ND)           // 576

#define LOG2E 1.4426950408889634f
// 1/sqrt(24) * log2(e): fold softmax scale and exp->exp2 conversion into Q
#define QSCALE (0.20412414523193152f * 1.4426950408889634f)

__device__ __forceinline__ u16 f2bf(float f){
  union { float f; unsigned u; } a; a.f = f;
  unsigned r = a.u + 0x7fffu + ((a.u >> 16) & 1u);   // round-to-nearest-even
  return (u16)(r >> 16);
}

__device__ __forceinline__ u32 cvtpk(float lo, float hi){
  u32 r; asm("v_cvt_pk_bf16_f32 %0, %1, %2" : "=v"(r) : "v"(lo), "v"(hi)); return r;
}
// swaps high 32 lanes of a with low 32 lanes of b:
// after: a = concat(a.lo, b.lo), b = concat(a.hi, b.hi)
__device__ __forceinline__ void pswap(u32 &a, u32 &b){
  asm("v_permlane32_swap_b32 %0, %1" : "+v"(a), "+v"(b));
}

// ---------------------------------------------------------------- prep ----
// seg A: x fp32 -> xb bf16 (1536 blocks)
// seg B: w_attn [192][576] -> wta [576][192] bf16, LDS-tiled transpose (27)
// seg C: w_proj [192][192] -> wtp [192][192] bf16 (9)
// seg D: Q[d24]=1.0, K[d24]=mask0*LOG2E  (256)
__device__ __forceinline__ void transpose64(
    const float* __restrict__ src, int srcN, u16* __restrict__ dst, int dstK,
    int k0, int n0, u16 (*sh)[68], int tid)
{
  int r = tid >> 2, cs = tid & 3;
  const float* sp = src + (size_t)(k0 + r)*srcN + n0 + cs*16;
  #pragma unroll
  for (int q = 0; q < 4; ++q) {
    float4 v = *(const float4*)(sp + q*4);
    u16 o[4] = { f2bf(v.x), f2bf(v.y), f2bf(v.z), f2bf(v.w) };
    *(u32x2*)&sh[r][cs*16 + q*4] = *(const u32x2*)o;
  }
  __syncthreads();
  int n = tid >> 2, ks = tid & 3;
  u16 tmp[16];
  #pragma unroll
  for (int j = 0; j < 16; ++j) tmp[j] = sh[ks*16 + j][n];
  u16* dp = dst + (size_t)(n0 + n)*dstK + k0 + ks*16;
  *(u32x4*)dp       = *(const u32x4*)tmp;
  *(u32x4*)(dp + 8) = *(const u32x4*)(tmp + 8);
}

__global__ __launch_bounds__(256) void prep_kernel(
    const float* __restrict__ x, const float* __restrict__ w_attn,
    const float* __restrict__ w_proj, const float* __restrict__ mask0,
    u16* __restrict__ xb, u16* __restrict__ wta, u16* __restrict__ wtp,
    u16* __restrict__ qp, u16* __restrict__ kp)
{
  __shared__ u16 sh[64][68];
  const int bid = blockIdx.x, tid = threadIdx.x;
  if (bid < 1536) {                                  // x -> bf16
    int i = bid*256 + tid;
    float4 v = reinterpret_cast<const float4*>(x)[i];
    u16 o[4] = { f2bf(v.x), f2bf(v.y), f2bf(v.z), f2bf(v.w) };
    *reinterpret_cast<u32x2*>(xb + (size_t)i*4) = *(const u32x2*)o;
  } else if (bid < 1536 + 27) {                      // w_attn transpose
    int t = bid - 1536; int kt = t/9, nt = t%9;
    transpose64(w_attn, N3, wta, ND, kt*64, nt*64, sh, tid);
  } else if (bid < 1536 + 27 + 9) {                  // w_proj transpose
    int t = bid - 1563; int kt = t/3, nt = t%3;
    transpose64(w_proj, ND, wtp, ND, kt*64, nt*64, sh, tid);
  } else {                                           // mask fold channel
    int i = (bid - 1572)*256 + tid;                  // 0..65535 = (b,s,h)
    int sg = i >> 3, h = i & 7;
    int b = sg >> 11, s = sg & (NS-1);
    size_t base = ((size_t)((b*NS + s)*NH + h))*32 + 24;
    qp[base] = 0x3F80;                               // 1.0 bf16
    kp[base] = f2bf(mask0[b*NS + s] * LOG2E);
  }
}

// ----------------------------------------------------------------- qkv ----
// [8192,192] @ [192,576] + b.  96-wide n-tiles (4 heads exactly).
// Q/K -> qp/kp [b][s][h][32] via LDS re-tile (coalesced 48B runs)
// V   -> vtp [b][h][d(32)][s] via per-lane 8B stores (s-innermost)
__global__ __launch_bounds__(256) void qkv_kernel(
    const u16* __restrict__ xb, const u16* __restrict__ wta,
    const float* __restrict__ b_attn,
    u16* __restrict__ qp, u16* __restrict__ kp, u16* __restrict__ vtp)
{
  __shared__ u16 tile[64][104];
  const int m0 = blockIdx.x*64, n0 = blockIdx.y*96;
  const int tid = threadIdx.x;
  const int w = tid >> 6, lane = tid & 63, c = lane & 15, g = lane >> 4;
  f32x4 acc[6] = {};
  const int ar = m0 + w*16 + c;
  #pragma unroll
  for (int ks = 0; ks < 6; ++ks) {
    bf16x8 af = *(const bf16x8*)(xb + (size_t)ar*ND + ks*32 + g*8);
    #pragma unroll
    for (int t = 0; t < 6; ++t) {
      bf16x8 bfr = *(const bf16x8*)(wta + (size_t)(n0 + t*16 + c)*ND + ks*32 + g*8);
      acc[t] = __builtin_amdgcn_mfma_f32_16x16x32_bf16(af, bfr, acc[t], 0, 0, 0);
    }
  }
  const int b = m0 >> 11, sb = m0 & (NS-1);
  if (n0 >= 384) {                                   // ---- V tiles ----
    #pragma unroll
    for (int t = 0; t < 6; ++t) {
      int n = n0 + t*16 + c, nv = n - 384;
      int hv = nv / HD, dv = nv % HD;
      float bias = b_attn[n];
      u16 o4[4];
      #pragma unroll
      for (int r = 0; r < 4; ++r) o4[r] = f2bf(acc[t][r] + bias);
      size_t idx = ((size_t)((b*NH + hv)*32 + dv))*NS + sb + w*16 + g*4;
      *(u32x2*)(vtp + idx) = *(const u32x2*)o4;
    }
  } else {                                           // ---- Q/K tiles ----
    const float scl = (n0 < 192) ? QSCALE : 1.0f;
    #pragma unroll
    for (int t = 0; t < 6; ++t) {
      float bias = b_attn[n0 + t*16 + c];
      #pragma unroll
      for (int r = 0; r < 4; ++r)
        tile[w*16 + g*4 + r][t*16 + c] = f2bf((acc[t][r] + bias)*scl);
    }
    __syncthreads();
    int row = tid >> 2, run = tid & 3;
    int hq = ((n0 % 192) / HD) + run;                // n0%192 in {0,96} -> h base 0/4
    u16* dst = ((n0 < 192) ? qp : kp)
             + ((size_t)((b*NS + sb + row)*NH + hq))*32;
    const u16* src = &tile[row][run*24];
    *(u32x4*)(dst)      = *(const u32x4*)(src);
    *(u32x4*)(dst + 8)  = *(const u32x4*)(src + 8);
    *(u32x4*)(dst + 16) = *(const u32x4*)(src + 16);
  }
}

// ---------------------------------------------------------------- attn ----
// 1 wave per block, 32 q-rows, kv-tiles of 32, no barriers in main loop.
// S^T = mfma(K,Q) so each lane holds a full k-slice of one q-column.
__global__ __launch_bounds__(64) void attn_kernel(
    const u16* __restrict__ qp, const u16* __restrict__ kp,
    const u16* __restrict__ vtp, u16* __restrict__ ao)
{
  __shared__ u16 ot[32][36];
  const int qt = 63 - (int)blockIdx.x;               // heavy tiles first
  const int bh = blockIdx.y;
  const int b = bh >> 3, h = bh & 7;
  const int lane = threadIdx.x, c = lane & 31, hi = lane >> 5;
  const int q0 = qt*32;

  const size_t rowstride = NH*32;                    // 256 u16 per s-row
  const size_t qkbase = (size_t)b*NS*rowstride + h*32;
  const size_t vbase  = ((size_t)(bh*32 + c))*NS;

  const u16* qrow = qp + qkbase + (size_t)(q0 + c)*rowstride;
  bf16x8 qf0 = *(const bf16x8*)(qrow + hi*8);
  bf16x8 qf1 = *(const bf16x8*)(qrow + 16 + hi*8);

  f32x16 o = {0};
  const f32x16 z16 = {0};
  float m = 0.f, l = 0.f;

  // prologue: tile 0 frags
  const u16* k0row = kp + qkbase + (size_t)c*rowstride;
  bf16x8 ka0 = *(const bf16x8*)(k0row + hi*8);
  bf16x8 ka1 = *(const bf16x8*)(k0row + 16 + hi*8);
  bf16x8 va0 = *(const bf16x8*)(vtp + vbase + hi*8);
  bf16x8 va1 = *(const bf16x8*)(vtp + vbase + 16 + hi*8);

  for (int jt = 0; jt <= qt; ++jt) {
    const int k0 = jt*32;
    const int kn = (jt < qt) ? k0 + 32 : k0;         // prefetch next (clamped)
    const u16* knrow = kp + qkbase + (size_t)(kn + c)*rowstride;
    bf16x8 kb0 = *(const bf16x8*)(knrow + hi*8);
    bf16x8 kb1 = *(const bf16x8*)(knrow + 16 + hi*8);
    bf16x8 vb0 = *(const bf16x8*)(vtp + vbase + kn + hi*8);
    bf16x8 vb1 = *(const bf16x8*)(vtp + vbase + kn + 16 + hi*8);

    f32x16 st = __builtin_amdgcn_mfma_f32_32x32x16_bf16(ka0, qf0, z16, 0, 0, 0);
    st        = __builtin_amdgcn_mfma_f32_32x32x16_bf16(ka1, qf1, st,  0, 0, 0);

    // causal mask (diag tile only) + per-lane max
    float pm = -3.0e38f;
    if (jt == qt) {
      #pragma unroll
      for (int r = 0; r < 16; ++r) {
        int krel = (r & 3) + 8*(r >> 2) + 4*hi;
        float s = (k0 + krel > q0 + c) ? -3.0e38f : st[r];
        st[r] = s; pm = fmaxf(pm, s);
      }
    } else {
      #pragma unroll
      for (int r = 0; r < 16; ++r) pm = fmaxf(pm, st[r]);
    }

    if (!__all(pm - m <= 8.f)) {                     // rare rescale path
      float pm2 = fmaxf(pm, __shfl_xor(pm, 32));
      float mn = fmaxf(m, pm2);
      float al = __builtin_amdgcn_exp2f(m - mn);
      #pragma unroll
      for (int r = 0; r < 16; ++r) o[r] *= al;
      l *= al; m = mn;
    }

    float ls = 0.f;
    #pragma unroll
    for (int r = 0; r < 16; ++r) {
      float p = __builtin_amdgcn_exp2f(st[r] - m);
      st[r] = p; ls += p;
    }
    l += ls;

    // P^T -> B-frags: cvt_pk pairs + permlane32_swap (fills 2 words each)
    u32 a0 = cvtpk(st[0], st[1]),  b0 = cvtpk(st[4], st[5]);
    u32 a1 = cvtpk(st[2], st[3]),  b1 = cvtpk(st[6], st[7]);
    pswap(a0, b0); pswap(a1, b1);
    u32 a2 = cvtpk(st[8], st[9]),  b2 = cvtpk(st[12], st[13]);
    u32 a3 = cvtpk(st[10], st[11]), b3 = cvtpk(st[14], st[15]);
    pswap(a2, b2); pswap(a3, b3);
    union { u32 w[4]; bf16x8 v; } pf0, pf1;
    pf0.w[0] = a0; pf0.w[1] = a1; pf0.w[2] = b0; pf0.w[3] = b1;
    pf1.w[0] = a2; pf1.w[1] = a3; pf1.w[2] = b2; pf1.w[3] = b3;

    o = __builtin_amdgcn_mfma_f32_32x32x16_bf16(va0, pf0.v, o, 0, 0, 0);
    o = __builtin_amdgcn_mfma_f32_32x32x16_bf16(va1, pf1.v, o, 0, 0, 0);

    ka0 = kb0; ka1 = kb1; va0 = vb0; va1 = vb1;
  }

  // epilogue: normalize, transpose O^T->O via tiny LDS, 24B stores
  float lt = l + __shfl_xor(l, 32);
  float inv = 1.0f / lt;
  #pragma unroll
  for (int r = 0; r < 16; ++r) {
    int d = (r & 3) + 8*(r >> 2) + 4*hi;
    if (d < HD) ot[c][d] = f2bf(o[r]*inv);
  }
  __syncthreads();
  int q = lane >> 1, half = lane & 1;
  const u16* src = &ot[q][half*12];
  u32x2 w0 = *(const u32x2*)src;
  u32x2 w1 = *(const u32x2*)(src + 4);
  u32x2 w2 = *(const u32x2*)(src + 8);
  u16* dst = ao + ((size_t)(b*NS + q0 + q))*ND + h*HD + half*12;
  *(u32x2*)dst       = w0;
  *(u32x2*)(dst + 4) = w1;
  *(u32x2*)(dst + 8) = w2;
}

// ---------------------------------------------------------------- proj ----
__global__ __launch_bounds__(256) void proj_kernel(
    const u16* __restrict__ ao, const u16* __restrict__ wtp,
    const float* __restrict__ bp, float* __restrict__ out)
{
  const int m0 = blockIdx.x*64, n0 = blockIdx.y*64;
  const int tid = threadIdx.x;
  const int w = tid >> 6, lane = tid & 63, c = lane & 15, g = lane >> 4;
  f32x4 acc[4] = {};
  const int ar = m0 + w*16 + c;
  #pragma unroll
  for (int ks = 0; ks < 6; ++ks) {
    bf16x8 af = *(const bf16x8*)(ao + (size_t)ar*ND + ks*32 + g*8);
    #pragma unroll
    for (int t = 0; t < 4; ++t) {
      bf16x8 bfr = *(const bf16x8*)(wtp + (size_t)(n0 + t*16 + c)*ND + ks*32 + g*8);
      acc[t] = __builtin_amdgcn_mfma_f32_16x16x32_bf16(af, bfr, acc[t], 0, 0, 0);
    }
  }
  #pragma unroll
  for (int t = 0; t < 4; ++t) {
    int n = n0 + t*16 + c;
    float bias = bp[n];
    #pragma unroll
    for (int r = 0; r < 4; ++r) {
      int mm = m0 + w*16 + g*4 + r;
      out[(size_t)mm*ND + n] = acc[t][r] + bias;
    }
  }
}

// -------------------------------------------------------------- launch ----
extern "C" void kernel_launch(void* const* d_in, const int* in_sizes, int n_in,
                              void* d_out, int out_size, void* d_ws, size_t ws_size,
                              hipStream_t stream)
{
  const float* x      = (const float*)d_in[0];
  const float* mask0  = (const float*)d_in[1];
  const float* w_attn = (const float*)d_in[2];
  const float* b_attn = (const float*)d_in[3];
  const float* w_proj = (const float*)d_in[4];
  const float* b_proj = (const float*)d_in[5];
  float* out = (float*)d_out;

  char* ws = (char*)d_ws;
  u16* qp  = (u16*)(ws);                                  // 4 MB [b][s][h][32]
  u16* kp  = (u16*)(ws + ((size_t)4  << 20));             // 4 MB [b][s][h][32]
  u16* vtp = (u16*)(ws + ((size_t)8  << 20));             // 4 MB [b][h][32][s]
  u16* xb  = (u16*)(ws + ((size_t)12 << 20));             // 3 MB x bf16
  u16* wta = (u16*)(ws + ((size_t)15 << 20));             // 216 KB
  u16* wtp = (u16*)(ws + ((size_t)15 << 20) + 256*1024);  // 72 KB
  u16* ao  = (u16*)(ws + ((size_t)15 << 20) + 512*1024);  // 3 MB attn out bf16

  // zero Q/K pad lanes d=25..31 (d=24 written by prep); vtp pads are unused
  hipMemsetAsync(ws, 0, (size_t)8 << 20, stream);

  prep_kernel<<<1828, 256, 0, stream>>>(x, w_attn, w_proj, mask0,
                                        xb, wta, wtp, qp, kp);
  qkv_kernel<<<dim3(NM/64, 6), 256, 0, stream>>>(xb, wta, b_attn, qp, kp, vtp);
  attn_kernel<<<dim3(64, NB*NH), 64, 0, stream>>>(qp, kp, vtp, ao);
  proj_kernel<<<dim3(NM/64, ND/64), 256, 0, stream>>>(ao, wtp, b_proj, out);
}